// Round 1
// baseline (211.635 us; speedup 1.0000x reference)
//
#include <hip/hip_runtime.h>
#include <hip/hip_bf16.h>
#include <stdint.h>

// WeightOnlyPerChannelQuantizedLinear: out[b,n] = (sum_k x[b,k]*w[n,k]) * scale[n]
// x: fp32 [16][8192], w: int8 values stored as int32 [28672][8192], scale: fp32 [28672]
// HBM-bound on the 940 MB int32 weight stream. bf16 MFMA 16x16x32; int8->bf16 is exact.

using f32x4 = __attribute__((ext_vector_type(4))) float;
using s16x8 = __attribute__((ext_vector_type(8))) short;

static constexpr int K      = 8192;
static constexpr int N      = 28672;
static constexpr int KSTEP  = 32;           // K per MFMA
static constexpr int NSTEPS = K / KSTEP;    // 256 k-steps total
static constexpr int WAVES  = 4;            // waves per block, split-K
static constexpr int KW     = K / WAVES;    // 2048 k per wave
static constexpr int SW     = KW / KSTEP;   // 64 MFMA steps per wave

// ---------------------------------------------------------------------------
// Pre-pass: fp32 activations [16][K] -> bf16 MFMA A-fragments (RNE rounding).
// Fragment layout for mfma_f32_16x16x32_bf16 A-operand:
//   lane l holds A[row = l&15][k = kk*32 + (l>>4)*8 + j], j=0..7, as 4 dwords
//   (bf16 pairs, even k in low half). Stored at afrag[kk*64 + l] (uint4).
// One lane's fragment = 16 contiguous bytes -> main kernel loads are dwordx4.
// ---------------------------------------------------------------------------
__global__ __launch_bounds__(256) void prep_a_kernel(const float* __restrict__ act,
                                                     uint4* __restrict__ afrag) {
  const int t   = blockIdx.x * 256 + threadIdx.x;  // 0 .. NSTEPS*64-1
  const int kk  = t >> 6;
  const int l   = t & 63;
  const int row = l & 15;
  const int q   = l >> 4;
  const float* src = act + row * K + kk * KSTEP + q * 8;
  uint d[4];
#pragma unroll
  for (int p = 0; p < 4; ++p) {
    uint u0 = __builtin_bit_cast(uint, src[2 * p]);
    uint u1 = __builtin_bit_cast(uint, src[2 * p + 1]);
    u0 += 0x7fffu + ((u0 >> 16) & 1u);            // RNE f32 -> bf16
    u1 += 0x7fffu + ((u1 >> 16) & 1u);
    d[p] = (u0 >> 16) | (u1 & 0xffff0000u);       // pack: even k low, odd k high
  }
  afrag[t] = make_uint4(d[0], d[1], d[2], d[3]);
}

// ---------------------------------------------------------------------------
// Main kernel: one block = 16 output channels, 4 waves split K in quarters.
// Per wave per K-step: 2x dwordx4 int32 weight load (8 contiguous words in
// row n0 + (l&15)) + 1x dwordx4 A-fragment load; convert int->f32->bf16
// (exact for |w|<=127); one MFMA. Epilogue: LDS reduce over 4 waves, scale.
// ---------------------------------------------------------------------------
__global__ __launch_bounds__(256) void wq_linear_kernel(
    const int* __restrict__ wt,        // int32 [N][K]
    const uint4* __restrict__ afrag,   // [NSTEPS][64]
    const float* __restrict__ scaler,  // [N]
    float* __restrict__ out) {         // [16][N]
  __shared__ float red[WAVES][256];
  const int tid = threadIdx.x;
  const int l   = tid & 63;
  const int w   = tid >> 6;
  const int n0  = blockIdx.x << 4;
  const int r   = l & 15;           // B-operand column (output channel within tile)
  const int q   = l >> 4;           // k-chunk selector

  const int*   wp = wt + (size_t)(n0 + r) * K + w * KW + q * 8;
  const uint4* ap = afrag + (size_t)(w * SW) * 64 + l;

  f32x4 acc = {0.f, 0.f, 0.f, 0.f};

#pragma unroll 4
  for (int s = 0; s < SW; ++s) {
    const uint4 av = ap[0];
    const int4  w0 = *(const int4*)(wp);
    const int4  w1 = *(const int4*)(wp + 4);
    ap += 64;       // next k-step's fragment block
    wp += KSTEP;    // 32 int32 ahead

    // int32 -> f32 (exact) ; bf16 = high 16 bits (exact for small ints)
    uint f0 = __builtin_bit_cast(uint, (float)w0.x);
    uint f1 = __builtin_bit_cast(uint, (float)w0.y);
    uint f2 = __builtin_bit_cast(uint, (float)w0.z);
    uint f3 = __builtin_bit_cast(uint, (float)w0.w);
    uint f4 = __builtin_bit_cast(uint, (float)w1.x);
    uint f5 = __builtin_bit_cast(uint, (float)w1.y);
    uint f6 = __builtin_bit_cast(uint, (float)w1.z);
    uint f7 = __builtin_bit_cast(uint, (float)w1.w);
    // pack bf16 pairs: even k low half, odd k high half
    uint b0 = (f0 >> 16) | (f1 & 0xffff0000u);
    uint b1 = (f2 >> 16) | (f3 & 0xffff0000u);
    uint b2 = (f4 >> 16) | (f5 & 0xffff0000u);
    uint b3 = (f6 >> 16) | (f7 & 0xffff0000u);

    s16x8 a = __builtin_bit_cast(s16x8, av);
    s16x8 b = __builtin_bit_cast(s16x8, make_uint4(b0, b1, b2, b3));
    acc = __builtin_amdgcn_mfma_f32_16x16x32_bf16(a, b, acc, 0, 0, 0);
  }

  // acc layout (m89-verified): col = l&15, row(batch) = (l>>4)*4 + i
#pragma unroll
  for (int i = 0; i < 4; ++i)
    red[w][(q * 4 + i) * 16 + r] = acc[i];
  __syncthreads();

  // thread t handles output element row = t>>4 (batch), col = t&15 (channel)
  const float sum = red[0][tid] + red[1][tid] + red[2][tid] + red[3][tid];
  const int col = tid & 15;
  const int row = tid >> 4;
  out[(size_t)row * N + n0 + col] = sum * scaler[n0 + col];
}

extern "C" void kernel_launch(void* const* d_in, const int* in_sizes, int n_in,
                              void* d_out, int out_size, void* d_ws, size_t ws_size,
                              hipStream_t stream) {
  const float* act    = (const float*)d_in[0];
  const int*   wt     = (const int*)d_in[1];
  const float* scaler = (const float*)d_in[2];
  float*       out    = (float*)d_out;
  uint4*       afrag  = (uint4*)d_ws;   // 256 KB of A-fragments

  prep_a_kernel<<<(NSTEPS * 64) / 256, 256, 0, stream>>>(act, afrag);
  wq_linear_kernel<<<N / 16, 256, 0, stream>>>(wt, afrag, scaler, out);
}